// Round 6
// baseline (102.384 us; speedup 1.0000x reference)
//
#include <hip/hip_runtime.h>
#include <hip/hip_bf16.h>

#define BB 256
#define NLAT 128
#define HH 64
#define CC 64
#define GG 5000
#define NG 4                // genes per block
#define GPAIR 2             // genes flushed together (contiguous in out)
#define NBLK (GG / NG)      // 1250 decoder blocks
#define GSTRIDE (GG * CC)   // 320000 floats between batch rows
#define BN_EPS 1e-5f

typedef __bf16 bf16x8 __attribute__((ext_vector_type(8)));
typedef float f32x4 __attribute__((ext_vector_type(4)));

// Kernel 1: h = BN(ReLU(latent @ W1 + b1)) -> bf16 [256][64]
__global__ void hprep_kernel(const float* __restrict__ latent,
                             const float* __restrict__ W1,
                             const float* __restrict__ b1,
                             const float* __restrict__ gamma,
                             const float* __restrict__ beta,
                             const float* __restrict__ mean,
                             const float* __restrict__ var,
                             unsigned short* __restrict__ hout) {
    const int b = blockIdx.x;   // 0..255
    const int c = threadIdx.x;  // 0..63
    float acc = b1[c];
    const float* lrow = latent + b * NLAT;
#pragma unroll 8
    for (int k = 0; k < NLAT; ++k)
        acc = fmaf(lrow[k], W1[k * HH + c], acc);
    acc = fmaxf(acc, 0.f);  // ReLU first
    float s = gamma[c] * rsqrtf(var[c] + BN_EPS);
    acc = (acc - mean[c]) * s + beta[c];
    __bf16 hv = (__bf16)acc;
    hout[b * HH + c] = *reinterpret_cast<unsigned short*>(&hv);
}

// Barrier that only drains LDS ops; global loads/stores stay in flight.
__device__ __forceinline__ void barrier_lds_only() {
    asm volatile("s_waitcnt lgkmcnt(0)" ::: "memory");
    __builtin_amdgcn_s_barrier();
    asm volatile("" ::: "memory");
}

// Kernel 2: out[b,g,c] = sum_h h[b,h] * W[gene,h,c] + bias[gene,c]
// 8 waves / 512 threads; wave w owns rows [w*32, w*32+32).
// NEW vs round 5: GPAIR=2 adjacent genes accumulated in a 128 KB LDS tile
// and flushed together -> every flush instr writes 2 rows x 512B CONTIGUOUS
// (2 genes x 256B adjacent in out[b][g][c]). ldsO is wave-local (each wave
// writes & flushes only its own 32 rows) -> no barriers on the output path;
// only the shared 16 KB W tile needs 2 lgkm-only barriers per group.
// 144 KB LDS -> 1 block/CU; stores stream across barriers (no vmcnt drain).
__global__ __launch_bounds__(512, 1) void decoder_kernel(
    const unsigned short* __restrict__ hbuf,  // bf16 [256][64]
    const int* __restrict__ genes,            // [5000]
    const float* __restrict__ wt,             // [30000][64][64] f32
    const float* __restrict__ bt,             // [30000][64] f32
    float* __restrict__ out)                  // [256][5000][64] f32
{
    __shared__ __align__(16) unsigned short ldsW[GPAIR * 4096];  // 16 KB
    __shared__ __align__(16) float ldsO[BB * GPAIR * CC];        // 128 KB

    const int tid = threadIdx.x;
    const int l   = tid & 63;
    const int w   = tid >> 6;   // wave 0..7
    const int l16 = l & 15;
    const int lg  = l >> 4;     // 0..3

    // Bijective chunked XCD swizzle (kept from round 5): NBLK = 1250.
    const int xcd = blockIdx.x & 7;
    const int kk  = blockIdx.x >> 3;
    const int v   = (xcd < 2 ? xcd * 157 : 314 + (xcd - 2) * 156) + kk;
    const int g0  = v * NG;

    // A fragments (persist): rows w*32 + m*16 + l16, k-contiguous 8 bf16
    bf16x8 afrag[2][2];
#pragma unroll
    for (int m = 0; m < 2; ++m)
#pragma unroll
        for (int ks = 0; ks < 2; ++ks) {
            int row = w * 32 + m * 16 + l16;
            afrag[m][ks] = *reinterpret_cast<const bf16x8*>(
                hbuf + row * HH + ks * 32 + lg * 8);
        }

    // W staging geometry: thread stages column sc of h-block shb, per gene.
    const int sc  = l;   // 0..63
    const int shb = w;   // 0..7
    const int swz16 = sc * 8 + (shb ^ (sc & 7));

    float pkv[GPAIR][8];

    // --- prologue: gather + stage group 0 (genes g0, g0+1)
#pragma unroll
    for (int ge = 0; ge < GPAIR; ++ge) {
        const float* Wg = wt + (size_t)genes[g0 + ge] * (HH * CC);
#pragma unroll
        for (int j = 0; j < 8; ++j)
            pkv[ge][j] = Wg[(shb * 8 + j) * CC + sc];
    }
#pragma unroll
    for (int ge = 0; ge < GPAIR; ++ge) {
        bf16x8 pk;
#pragma unroll
        for (int j = 0; j < 8; ++j) pk[j] = (__bf16)pkv[ge][j];
        *reinterpret_cast<bf16x8*>(
            reinterpret_cast<char*>(ldsW) + ge * 8192 + swz16 * 16) = pk;
    }
    barrier_lds_only();

#pragma unroll
    for (int i = 0; i < NG / GPAIR; ++i) {  // 2 groups
        const int gg = g0 + i * GPAIR;
        const bool havenext = (i + 1 < NG / GPAIR);

        // 1. issue next group's gather loads early (hide under MFMA+flush)
        if (havenext) {
#pragma unroll
            for (int ge = 0; ge < GPAIR; ++ge) {
                const float* Wn =
                    wt + (size_t)genes[gg + GPAIR + ge] * (HH * CC);
#pragma unroll
                for (int j = 0; j < 8; ++j)
                    pkv[ge][j] = Wn[(shb * 8 + j) * CC + sc];
            }
        }

        // 2. MFMA both genes (operand-swapped):
        //    E[ge][n][m] lane -> b = w*32+m*16+l16, c = n*16+lg*4+r
        f32x4 E[GPAIR][4][2];
#pragma unroll
        for (int ge = 0; ge < GPAIR; ++ge) {
            const float* bg = bt + (size_t)genes[gg + ge] * CC;
            const char* buf = reinterpret_cast<const char*>(ldsW) + ge * 8192;
#pragma unroll
            for (int n = 0; n < 4; ++n) {
                const int c = n * 16 + l16;
                bf16x8 bfr0 = *reinterpret_cast<const bf16x8*>(
                    buf + (c * 8 + ((0 + lg) ^ (c & 7))) * 16);
                bf16x8 bfr1 = *reinterpret_cast<const bf16x8*>(
                    buf + (c * 8 + ((4 + lg) ^ (c & 7))) * 16);
                f32x4 binit = *reinterpret_cast<const f32x4*>(bg + n * 16 + lg * 4);
#pragma unroll
                for (int m = 0; m < 2; ++m) {
                    f32x4 e = binit;
                    e = __builtin_amdgcn_mfma_f32_16x16x32_bf16(bfr0, afrag[m][0], e, 0, 0, 0);
                    e = __builtin_amdgcn_mfma_f32_16x16x32_bf16(bfr1, afrag[m][1], e, 0, 0, 0);
                    E[ge][n][m] = e;
                }
            }
        }

        // 3. E -> ldsO (wave-local rows; row = 512B = 32 x 16B units)
        //    unit-in-row = ge*16 + ((n*4+lg) ^ (row&15)), row&15 == l16
#pragma unroll
        for (int ge = 0; ge < GPAIR; ++ge)
#pragma unroll
            for (int n = 0; n < 4; ++n)
#pragma unroll
                for (int m = 0; m < 2; ++m) {
                    int bl = w * 32 + m * 16 + l16;
                    int unit = bl * 32 + ge * 16 + ((n * 4 + lg) ^ l16);
                    *reinterpret_cast<f32x4*>(ldsO + unit * 4) = E[ge][n][m];
                }

        // 4. flush (wave-local, no barrier): each instr = 2 rows x 512B
        //    contiguous (2 genes x 256B adjacent in out layout)
        {
            float* og = out + (size_t)gg * CC;
            const int p   = l & 31;   // 16B-unit position within 512B run
            const int gi2 = p >> 4;   // gene within pair
            const int x   = p & 15;   // c-quad
            const int rh  = l >> 5;   // row half
#pragma unroll
            for (int it = 0; it < 16; ++it) {
                int bl = w * 32 + it * 2 + rh;
                int unit = bl * 32 + gi2 * 16 + (x ^ (bl & 15));
                f32x4 vv = *reinterpret_cast<const f32x4*>(ldsO + unit * 4);
                *reinterpret_cast<f32x4*>(og + (size_t)bl * GSTRIDE + p * 4) = vv;
            }
        }

        // 5. restage W for next group (stores keep flying; lgkm-only barriers)
        if (havenext) {
            barrier_lds_only();  // all waves done reading current ldsW
#pragma unroll
            for (int ge = 0; ge < GPAIR; ++ge) {
                bf16x8 pk;
#pragma unroll
                for (int j = 0; j < 8; ++j) pk[j] = (__bf16)pkv[ge][j];
                *reinterpret_cast<bf16x8*>(
                    reinterpret_cast<char*>(ldsW) + ge * 8192 + swz16 * 16) = pk;
            }
            barrier_lds_only();  // new W visible to all waves
        }
    }
}

extern "C" void kernel_launch(void* const* d_in, const int* in_sizes, int n_in,
                              void* d_out, int out_size, void* d_ws, size_t ws_size,
                              hipStream_t stream) {
    const float* latent = (const float*)d_in[0];
    const int*   genes  = (const int*)d_in[1];
    const float* W1     = (const float*)d_in[2];
    const float* b1     = (const float*)d_in[3];
    const float* gamma  = (const float*)d_in[4];
    const float* beta   = (const float*)d_in[5];
    const float* mean   = (const float*)d_in[6];
    const float* var    = (const float*)d_in[7];
    const float* wt     = (const float*)d_in[8];
    const float* bt     = (const float*)d_in[9];
    float* out = (float*)d_out;
    unsigned short* hbuf = (unsigned short*)d_ws;  // 32 KB bf16 h

    hprep_kernel<<<dim3(BB), dim3(HH), 0, stream>>>(latent, W1, b1, gamma, beta,
                                                    mean, var, hbuf);
    decoder_kernel<<<dim3(NBLK), dim3(512), 0, stream>>>(hbuf, genes, wt, bt, out);
}

// Round 7
// 77.104 us; speedup vs baseline: 1.3279x; 1.3279x over previous
//
#include <hip/hip_runtime.h>
#include <hip/hip_bf16.h>

#define BB 256
#define NLAT 128
#define HH 64
#define CC 64
#define GG 5000
#define NG 4
#define NBLK (GG / NG)      // 1250 decoder blocks
#define GSTRIDE (GG * CC)   // 320000 floats between batch rows
#define BN_EPS 1e-5f

typedef __bf16 bf16x8 __attribute__((ext_vector_type(8)));
typedef float f32x4 __attribute__((ext_vector_type(4)));

// Kernel 1: h = BN(ReLU(latent @ W1 + b1)) -> bf16 [256][64]
__global__ void hprep_kernel(const float* __restrict__ latent,
                             const float* __restrict__ W1,
                             const float* __restrict__ b1,
                             const float* __restrict__ gamma,
                             const float* __restrict__ beta,
                             const float* __restrict__ mean,
                             const float* __restrict__ var,
                             unsigned short* __restrict__ hout) {
    const int b = blockIdx.x;   // 0..255
    const int c = threadIdx.x;  // 0..63
    float acc = b1[c];
    const float* lrow = latent + b * NLAT;
#pragma unroll 8
    for (int k = 0; k < NLAT; ++k)
        acc = fmaf(lrow[k], W1[k * HH + c], acc);
    acc = fmaxf(acc, 0.f);  // ReLU first
    float s = gamma[c] * rsqrtf(var[c] + BN_EPS);
    acc = (acc - mean[c]) * s + beta[c];
    __bf16 hv = (__bf16)acc;
    hout[b * HH + c] = *reinterpret_cast<unsigned short*>(&hv);
}

// Barrier that only drains LDS ops; global loads/stores stay in flight.
__device__ __forceinline__ void barrier_lds_only() {
    asm volatile("s_waitcnt lgkmcnt(0)" ::: "memory");
    __builtin_amdgcn_s_barrier();
    asm volatile("" ::: "memory");
}

// Kernel 2: out[b,g,c] = sum_h h[b,h] * W[gene,h,c] + bias[gene,c]
// Round-5 structure (99.5 us, best so far): 8 waves / 512 threads; wave w
// owns rows [w*32, w*32+32); operand-swapped MFMA; per-gene 64 KB LDS
// output tile flushed as full 256B-per-b-row segments; chunked bijective
// XCD swizzle. NEW (single variable): the flush uses NON-TEMPORAL stores.
// Theory: normal stores retire via per-XCD write-back L2, and DRAM sees the
// (scrambled) eviction order of a sparse 256B-granule dirty set -> row-miss
// bound (~59% eff). nt stores demote L2 residency so the write stream hits
// the memory controllers near program order (b-ascending 256B segments),
// and stop thrashing L2 for the W/h read streams.
__global__ __launch_bounds__(512, 4) void decoder_kernel(
    const unsigned short* __restrict__ hbuf,  // bf16 [256][64]
    const int* __restrict__ genes,            // [5000]
    const float* __restrict__ wt,             // [30000][64][64] f32
    const float* __restrict__ bt,             // [30000][64] f32
    float* __restrict__ out)                  // [256][5000][64] f32
{
    __shared__ __align__(16) unsigned short ldsW[2][4096];  // 2 x 8 KB bf16 Wt
    __shared__ __align__(16) float ldsO[BB * CC];           // 64 KB out tile

    const int tid = threadIdx.x;
    const int l   = tid & 63;
    const int w   = tid >> 6;   // wave 0..7
    const int l16 = l & 15;
    const int lg  = l >> 4;     // 0..3

    // Bijective chunked XCD swizzle: NBLK = 1250 = 8*156 + 2.
    const int xcd = blockIdx.x & 7;
    const int k   = blockIdx.x >> 3;
    const int v   = (xcd < 2 ? xcd * 157 : 314 + (xcd - 2) * 156) + k;
    const int g0  = v * NG;

    // A fragments (persist): rows w*32 + m*16 + l16, k-contiguous 8 bf16
    bf16x8 afrag[2][2];
#pragma unroll
    for (int m = 0; m < 2; ++m)
#pragma unroll
        for (int ks = 0; ks < 2; ++ks) {
            int row = w * 32 + m * 16 + l16;
            afrag[m][ks] = *reinterpret_cast<const bf16x8*>(
                hbuf + row * HH + ks * 32 + lg * 8);
        }

    // W staging geometry: thread stages column sc of h-block shb.
    const int sc  = l;   // 0..63
    const int shb = w;   // 0..7
    const int swz16 = sc * 8 + (shb ^ (sc & 7));

    float pkv[8];

    // --- prologue: stage gene g0 into ldsW[0]
    {
        const float* Wg = wt + (size_t)genes[g0] * (HH * CC);
#pragma unroll
        for (int j = 0; j < 8; ++j)
            pkv[j] = Wg[(shb * 8 + j) * CC + sc];
        bf16x8 pk;
#pragma unroll
        for (int j = 0; j < 8; ++j) pk[j] = (__bf16)pkv[j];
        *reinterpret_cast<bf16x8*>(
            reinterpret_cast<char*>(ldsW[0]) + swz16 * 16) = pk;
    }
    barrier_lds_only();

    int p = 0;
#pragma unroll
    for (int i = 0; i < NG; ++i) {
        const int g = g0 + i;

        // 1. issue next gene's gather loads early (hide under MFMA + flush)
        if (i + 1 < NG) {
            const float* Wn = wt + (size_t)genes[g + 1] * (HH * CC);
#pragma unroll
            for (int j = 0; j < 8; ++j)
                pkv[j] = Wn[(shb * 8 + j) * CC + sc];
        }

        // 2. MFMA (operand-swapped): E[n][m] lane = (c = n*16+lg*4+r, b = l16)
        const float* bg = bt + (size_t)genes[g] * CC;
        const char* buf = reinterpret_cast<const char*>(ldsW[p]);
        f32x4 E[4][2];
#pragma unroll
        for (int n = 0; n < 4; ++n) {
            const int c = n * 16 + l16;
            bf16x8 bfr0 = *reinterpret_cast<const bf16x8*>(
                buf + (c * 8 + ((0 + lg) ^ (c & 7))) * 16);
            bf16x8 bfr1 = *reinterpret_cast<const bf16x8*>(
                buf + (c * 8 + ((4 + lg) ^ (c & 7))) * 16);
            f32x4 binit = *reinterpret_cast<const f32x4*>(bg + n * 16 + lg * 4);
#pragma unroll
            for (int m = 0; m < 2; ++m) {
                f32x4 e = binit;
                e = __builtin_amdgcn_mfma_f32_16x16x32_bf16(bfr0, afrag[m][0], e, 0, 0, 0);
                e = __builtin_amdgcn_mfma_f32_16x16x32_bf16(bfr1, afrag[m][1], e, 0, 0, 0);
                E[n][m] = e;
            }
        }

        // 3. acc -> ldsO, chunk-XOR swizzled (2-way max = free)
#pragma unroll
        for (int n = 0; n < 4; ++n)
#pragma unroll
            for (int m = 0; m < 2; ++m) {
                int b = w * 32 + m * 16 + l16;
                int qp = (n * 4 + lg) ^ l16;
                *reinterpret_cast<f32x4*>(ldsO + b * CC + qp * 4) = E[n][m];
            }
        barrier_lds_only();

        // 4. flush (NON-TEMPORAL): 16 lanes cover one full 256B (b,g) row
        {
            float* og = out + (size_t)g * CC;
#pragma unroll
            for (int it = 0; it < 8; ++it) {
                int b  = it * 32 + w * 4 + lg;
                int qp = l16 ^ (b & 15);
                f32x4 vv = *reinterpret_cast<const f32x4*>(ldsO + b * CC + qp * 4);
                __builtin_nontemporal_store(
                    vv, reinterpret_cast<f32x4*>(og + (size_t)b * GSTRIDE + l16 * 4));
            }
        }

        // 5. cvt + ds_write next gene's Wt (stores keep flying)
        if (i + 1 < NG) {
            bf16x8 pk;
#pragma unroll
            for (int j = 0; j < 8; ++j) pk[j] = (__bf16)pkv[j];
            *reinterpret_cast<bf16x8*>(
                reinterpret_cast<char*>(ldsW[p ^ 1]) + swz16 * 16) = pk;
            p ^= 1;
        }
        barrier_lds_only();  // protects ldsO reuse + Wt buffer handoff
    }
}

extern "C" void kernel_launch(void* const* d_in, const int* in_sizes, int n_in,
                              void* d_out, int out_size, void* d_ws, size_t ws_size,
                              hipStream_t stream) {
    const float* latent = (const float*)d_in[0];
    const int*   genes  = (const int*)d_in[1];
    const float* W1     = (const float*)d_in[2];
    const float* b1     = (const float*)d_in[3];
    const float* gamma  = (const float*)d_in[4];
    const float* beta   = (const float*)d_in[5];
    const float* mean   = (const float*)d_in[6];
    const float* var    = (const float*)d_in[7];
    const float* wt     = (const float*)d_in[8];
    const float* bt     = (const float*)d_in[9];
    float* out = (float*)d_out;
    unsigned short* hbuf = (unsigned short*)d_ws;  // 32 KB bf16 h

    hprep_kernel<<<dim3(BB), dim3(HH), 0, stream>>>(latent, W1, b1, gamma, beta,
                                                    mean, var, hbuf);
    decoder_kernel<<<dim3(NBLK), dim3(512), 0, stream>>>(hbuf, genes, wt, bt, out);
}